// Round 3
// baseline (407.841 us; speedup 1.0000x reference)
//
#include <hip/hip_runtime.h>
#include <cstdint>

// Problem constants
#define BATCH   2
#define T_SEQ   2048
#define NH      16
#define DK      128
#define DMODEL  2048   // NH*DK
#define NQKV    6144   // 3*DMODEL

using short8 = __attribute__((ext_vector_type(8))) short;   // 8 bf16 (4 VGPRs)
using f32x4  = __attribute__((ext_vector_type(4))) float;   // 16x16 MFMA C/D
using f32x16 = __attribute__((ext_vector_type(16))) float;  // 32x32 MFMA C/D

__device__ __forceinline__ float bf2f(unsigned short u) {
    union { float f; uint32_t i; } x; x.i = ((uint32_t)u) << 16; return x.f;
}
__device__ __forceinline__ unsigned short f2bf(float f) {
    union { float f; uint32_t i; } x; x.f = f;
    uint32_t r = x.i + 0x7fffu + ((x.i >> 16) & 1u);   // RNE (no NaN inputs here)
    return (unsigned short)(r >> 16);
}

// async global->LDS, 16B per lane. LDS dest = wave-uniform base + lane*16 (m104/m108).
__device__ __forceinline__ void async_load16(const unsigned short* g, unsigned short* l) {
    __builtin_amdgcn_global_load_lds(
        (const __attribute__((address_space(1))) unsigned int*)g,
        (__attribute__((address_space(3))) unsigned int*)l,
        16, 0, 0);
}

// ---------------------------------------------------------------- prep kernels

__global__ void cast_x_kernel(const float* __restrict__ x,
                              unsigned short* __restrict__ xb, int n4) {
    int i = blockIdx.x * 256 + threadIdx.x;
    if (i >= n4) return;
    float4 v = ((const float4*)x)[i];
    ushort4 o;
    o.x = f2bf(v.x); o.y = f2bf(v.y); o.z = f2bf(v.z); o.w = f2bf(v.w);
    ((ushort4*)xb)[i] = o;
}

// W (K,N) fp32 row-major -> WT (N,K) bf16 row-major (for gemm_bt B-frag reads)
__global__ void wtrans_kernel(const float* __restrict__ W,
                              unsigned short* __restrict__ WT, int K, int N) {
    __shared__ unsigned short tile[64][65];  // +1 pad
    int k0 = blockIdx.y * 64, n0 = blockIdx.x * 64;
    for (int it = 0; it < 16; ++it) {
        int idx = it * 256 + threadIdx.x;
        int r = idx >> 6, c = idx & 63;                       // r: k-row, c: n-col
        tile[r][c] = f2bf(W[(size_t)(k0 + r) * N + n0 + c]);  // coalesced in n
    }
    __syncthreads();
    for (int it = 0; it < 16; ++it) {
        int idx = it * 256 + threadIdx.x;
        int r = idx >> 6, c = idx & 63;                       // r: n-row of WT, c: k-col
        WT[(size_t)(n0 + r) * K + k0 + c] = tile[c][r];       // coalesced in k
    }
}

// ---------------------------------------------------------------- GEMM (legacy 128x128, used for GEMM2)
template <int MODE>
__global__ __launch_bounds__(256) void gemm_bt_kernel(
    const unsigned short* __restrict__ A, const unsigned short* __restrict__ BT,
    float* __restrict__ Cout,
    unsigned short* __restrict__ qraw, unsigned short* __restrict__ kraw,
    unsigned short* __restrict__ vtb,
    int M, int N, int K) {
    __shared__ __align__(16) unsigned short As[128 * 64];
    __shared__ __align__(16) unsigned short Bs[128 * 64];
    const int tid = threadIdx.x;
    const int w = tid >> 6, lane = tid & 63;
    const int l31 = lane & 31, lhi = lane >> 5;
    const int m0 = blockIdx.y * 128, n0 = blockIdx.x * 128;
    const int wm = (w & 1) * 64, wn = (w >> 1) * 64;

    f32x16 acc[2][2];
#pragma unroll
    for (int a = 0; a < 2; ++a)
#pragma unroll
        for (int b = 0; b < 2; ++b)
#pragma unroll
            for (int r = 0; r < 16; ++r) acc[a][b][r] = 0.f;

    for (int k0 = 0; k0 < K; k0 += 64) {
#pragma unroll
        for (int j = 0; j < 4; ++j) {
            int c   = (w * 4 + j) * 64 + lane;   // chunk id 0..1023
            int row = c >> 3;
            int kcg = (c & 7) ^ (row & 7);       // swizzled global 16B column-chunk
            async_load16(A  + (size_t)(m0 + row) * K + k0 + kcg * 8,
                         As + (size_t)(w * 4 + j) * 64 * 8);
            async_load16(BT + (size_t)(n0 + row) * K + k0 + kcg * 8,
                         Bs + (size_t)(w * 4 + j) * 64 * 8);
        }
        __syncthreads();   // drains vmcnt for global_load_lds
#pragma unroll
        for (int ks = 0; ks < 4; ++ks) {         // 4 k-steps of 16
            short8 af[2], bfr[2];
#pragma unroll
            for (int mt = 0; mt < 2; ++mt) {
                int row = wm + mt * 32 + l31;
                int kcs = (ks * 2 + lhi) ^ (row & 7);
                af[mt] = *(const short8*)(As + row * 64 + kcs * 8);
            }
#pragma unroll
            for (int nt = 0; nt < 2; ++nt) {
                int row = wn + nt * 32 + l31;
                int kcs = (ks * 2 + lhi) ^ (row & 7);
                bfr[nt] = *(const short8*)(Bs + row * 64 + kcs * 8);
            }
#pragma unroll
            for (int mt = 0; mt < 2; ++mt)
#pragma unroll
                for (int nt = 0; nt < 2; ++nt)
                    acc[mt][nt] = __builtin_amdgcn_mfma_f32_32x32x16_bf16(
                        af[mt], bfr[nt], acc[mt][nt], 0, 0, 0);
        }
        __syncthreads();
    }

    if (MODE == 0) {
#pragma unroll
        for (int mt = 0; mt < 2; ++mt)
#pragma unroll
            for (int nt = 0; nt < 2; ++nt)
#pragma unroll
                for (int r = 0; r < 16; ++r) {
                    int row = m0 + wm + mt * 32 + (r & 3) + 8 * (r >> 2) + 4 * lhi;
                    int col = n0 + wn + nt * 32 + l31;
                    Cout[(size_t)row * N + col] = acc[mt][nt][r];
                }
    }
}

// ---------------------------------------------------------------- GEMM1: 256x256 8-phase
// Round-3 rev: 32x32x16 MFMA (2495 vs 2075 TF rate) + balanced reads via
// pre-reading the next quadrant's A-half in the previously-empty P3/P7 slots.
// BK=64, 8 waves (2M x 4N), wave tile 128x64 = 4x2 of 32x32.
// Reads/phase/wave: 4/4/8/8pre/4/4/8/8pre (was 12/4/8/0). Pre-reads sit
// AFTER the vmcnt wait (data landed — see ledger) and execute during the
// barrier rendezvous, overlapping other waves' MFMA.
// Staging schedule & vmcnt ledger IDENTICAL to the round-1/2 passing kernels:
//   P0:A1h1(t+1) P1:B1h1(t+1) P2:A0h0(t+2) P3:B0h0(t+2) [vm4 -> buf1(t+1) landed]
//   P4:A0h1(t+2) P5:B0h1(t+2) P6:A1h0(t+3) P7:B1h0(t+3) [vm4 -> buf0(t+2) landed]
// Pre-read RAW: P3 reads buf1-Ah0 (landed at P3 vm4); P7 reads buf0-Ah0
// (landed at P7 vm4). WAR: those regions are restaged >=3 barriers after
// their last consumer (P6 / next-P2). OK.
#define G1_K 2048
#define G1_N 6144

__global__ __launch_bounds__(512, 2) void gemm8p_qkv_kernel(
    const unsigned short* __restrict__ A, const unsigned short* __restrict__ BT,
    unsigned short* __restrict__ qraw, unsigned short* __restrict__ kraw,
    unsigned short* __restrict__ vtb) {
    __shared__ __align__(16) unsigned short As[2][256 * 64];   // 64 KiB
    __shared__ __align__(16) unsigned short Bs[2][256 * 64];   // 64 KiB

    const int tid = threadIdx.x;
    const int w = tid >> 6, lane = tid & 63;
    const int l31 = lane & 31, lhi = lane >> 5, l7 = lane & 7;
    const int wm = (w & 1) * 128, wn = (w >> 1) * 64;

    // XCD swizzle (384 % 8 == 0, bijective) then row-major over 16x24 tiles.
    const int id = blockIdx.x;
    const int wg = (id & 7) * 48 + (id >> 3);
    const int by = wg / 24, bx = wg - by * 24;
    const int m0 = by * 256, n0 = bx * 256;

    // staging geometry: 512 thr x 16B = 64 rows/issue; global chunk pre-swizzle
    const int r64 = tid >> 3;                    // row within 64-row issue
    const int csw = (tid & 7) ^ (r64 & 7);       // swizzled source 16B chunk

    auto stageA = [&](int buf, int kt, int h) {  // A-half h = rows bit6==h
#pragma unroll
        for (int j = 0; j < 2; ++j) {
            const int rg = h * 64 + j * 128 + r64;
            async_load16(A + (size_t)(m0 + rg) * G1_K + kt * 64 + csw * 8,
                         &As[buf][(h * 64 + j * 128 + w * 8) << 6]);
        }
    };
    auto stageB = [&](int buf, int kt, int h) {  // B-half h = rows bit5==h
#pragma unroll
        for (int j = 0; j < 2; ++j) {
            const int rbw = j * 128 + ((w >> 2) << 6) + h * 32 + ((w & 3) << 3);
            const int rg  = rbw + (lane >> 3);
            async_load16(BT + (size_t)(n0 + rg) * G1_K + kt * 64 + csw * 8,
                         &Bs[buf][rbw << 6]);
        }
    };

    f32x16 acc[4][2];
#pragma unroll
    for (int i = 0; i < 4; ++i)
#pragma unroll
        for (int j = 0; j < 2; ++j)
#pragma unroll
            for (int r = 0; r < 16; ++r) acc[i][j][r] = 0.f;

    short8 paf[2][4], pbf0[4], pbf1[4];

// A-frag (32x32x16): elem[m=lane&31][k=(lane>>5)*8+j]; rows wm+H*64+{0,32}+l31
#define LOADA32(BUF, H)                                                         \
  _Pragma("unroll") for (int mt = 0; mt < 2; ++mt)                              \
    _Pragma("unroll") for (int ks = 0; ks < 4; ++ks)                            \
      paf[mt][ks] = *(const short8*)(&As[BUF][((wm + (H)*64 + mt*32 + l31)      \
          << 6) + (((ks*2 + lhi) ^ l7) << 3)]);

#define LOADB32(BUF, H, DST)                                                    \
  _Pragma("unroll") for (int ks = 0; ks < 4; ++ks)                              \
    DST[ks] = *(const short8*)(&Bs[BUF][((wn + (H)*32 + l31) << 6)              \
        + (((ks*2 + lhi) ^ l7) << 3)]);

#define MFMAQ32(QM, QN, PB)                                                     \
  __builtin_amdgcn_s_setprio(1);                                                \
  _Pragma("unroll") for (int mt = 0; mt < 2; ++mt)                              \
    _Pragma("unroll") for (int ks = 0; ks < 4; ++ks)                            \
      acc[(QM)*2 + mt][QN] = __builtin_amdgcn_mfma_f32_32x32x16_bf16(           \
          paf[mt][ks], PB[ks], acc[(QM)*2 + mt][QN], 0, 0, 0);                  \
  __builtin_amdgcn_s_setprio(0);

#define LGK0 asm volatile("s_waitcnt lgkmcnt(0)" ::: "memory");                 \
             __builtin_amdgcn_sched_barrier(0)
#define BAR  __builtin_amdgcn_s_barrier()
#define VM4  asm volatile("s_waitcnt vmcnt(4)" ::: "memory")
#define VM0  asm volatile("s_waitcnt vmcnt(0)" ::: "memory")

    // prologue: tile0 fully + A0,B0 of tile1; retire tile0 (vm4), pre-read A-h0
    stageA(0, 0, 0); stageB(0, 0, 0); stageA(0, 0, 1); stageB(0, 0, 1);
    stageA(1, 1, 0); stageB(1, 1, 0);
    VM4;
    LOADA32(0, 0)        // buf0 A-h0 landed; head start for P0
    BAR;

    const int NI = G1_K / 128;   // 16 iterations, 2 K-tiles each
    for (int it = 0; it < NI; ++it) {
        const int t1 = 2 * it + 1;
        const bool last = (it == NI - 1);
        // ---------------- buffer 0 = tile 2it, Gray order (0,0)(0,1)(1,1)(1,0)
        // P0: A-h0 pre-read last phase; load B-h0
        LOADB32(0, 0, pbf0)
        stageA(1, t1, 1);
        BAR; LGK0;
        MFMAQ32(0, 0, pbf0)
        BAR;
        // P1: load B-h1 (A-h0 cached)
        LOADB32(0, 1, pbf1)
        stageB(1, t1, 1);
        BAR; LGK0;
        MFMAQ32(0, 1, pbf1)
        BAR;
        // P2: load A-h1 (B-h1 cached)
        LOADA32(0, 1)
        if (!last) stageA(0, t1 + 1, 0);
        BAR; LGK0;
        MFMAQ32(1, 1, pbf1)
        BAR;
        // P3: no loads before MFMA (A-h1 + B-h0 cached); after vm wait,
        // pre-read buf1 A-h0 (landed) — overlaps barrier rendezvous
        if (!last) stageB(0, t1 + 1, 0);
        BAR;
        MFMAQ32(1, 0, pbf0)
        if (last) { VM0; } else { VM4; }   // buf1(t1) fully landed
        LOADA32(1, 0)
        BAR;
        // ---------------- buffer 1 = tile 2it+1
        // P4
        LOADB32(1, 0, pbf0)
        if (!last) stageA(0, t1 + 1, 1);
        BAR; LGK0;
        MFMAQ32(0, 0, pbf0)
        BAR;
        // P5
        LOADB32(1, 1, pbf1)
        if (!last) stageB(0, t1 + 1, 1);
        BAR; LGK0;
        MFMAQ32(0, 1, pbf1)
        BAR;
        // P6
        LOADA32(1, 1)
        if (!last) stageA(1, t1 + 2, 0);
        BAR; LGK0;
        MFMAQ32(1, 1, pbf1)
        BAR;
        // P7
        if (!last) stageB(1, t1 + 2, 0);
        BAR;
        MFMAQ32(1, 0, pbf0)
        if (!last) {
            VM4;                           // buf0(t1+1) fully landed
            LOADA32(0, 0)                  // pre-read for next iter's P0
        }
        BAR;
    }

    // epilogue: scatter qkv. 32x32 C/D layout (m74/m101): col = lane&31,
    // row = (r&3) + 8*(r>>2) + 4*(lane>>5). qkv col -> head h = col/384;
    // [0,128) q, [128,256) k, [256,384) v; 32-col tiles never straddle.
#pragma unroll
    for (int mt = 0; mt < 4; ++mt) {
        const int trowb = m0 + wm + mt * 32;      // 32-row tile, within one batch
        const int bi = trowb >> 11;
        const int tb = trowb & (T_SEQ - 1);
#pragma unroll
        for (int nt = 0; nt < 2; ++nt) {
            const int colb = n0 + wn + nt * 32;
            const int h    = colb / 384;
            const int r3   = colb - h * 384;
            const int sec  = r3 >> 7;
            const int dk   = (r3 & 127) + l31;
            if (sec < 2) {
                unsigned short* dst = (sec == 0 ? qraw : kraw) +
                    ((size_t)(bi * NH + h) * T_SEQ + tb) * DK + dk;
#pragma unroll
                for (int r = 0; r < 16; ++r) {
                    int t = (r & 3) + 8 * (r >> 2) + 4 * lhi;
                    dst[(size_t)t * DK] = f2bf(acc[mt][nt][r]);
                }
            } else {
                // V stored transposed (B,H,DK,T): regs 4g..4g+3 are 4
                // consecutive t -> one 8B store per group
                unsigned short* dst =
                    vtb + ((size_t)(bi * NH + h) * DK + dk) * T_SEQ + tb;
#pragma unroll
                for (int g = 0; g < 4; ++g) {
                    ushort4 p;
                    p.x = f2bf(acc[mt][nt][4 * g + 0]);
                    p.y = f2bf(acc[mt][nt][4 * g + 1]);
                    p.z = f2bf(acc[mt][nt][4 * g + 2]);
                    p.w = f2bf(acc[mt][nt][4 * g + 3]);
                    *(ushort4*)(dst + 8 * g + 4 * lhi) = p;
                }
            }
        }
    }
#undef LOADA32
#undef LOADB32
#undef MFMAQ32
#undef LGK0
#undef BAR
#undef VM4
#undef VM0
}

// ---------------------------------------------------------------- RoPE (in place)
__global__ void rope_kernel(unsigned short* __restrict__ qraw,
                            unsigned short* __restrict__ kraw,
                            const float* __restrict__ freqs) {
    int linear = blockIdx.x * 256 + threadIdx.x;   // ((b*NH+h)*T + t)*64 + i
    int i  = linear & 63;
    int t  = (linear >> 6) & (T_SEQ - 1);
    int bh = linear >> 17;
    int b  = bh >> 4;
    float f  = freqs[((size_t)b * T_SEQ + t) * 64 + i];
    float cs = __cosf(f), sn = __sinf(f);
    size_t off = ((size_t)bh * T_SEQ + t) * DK + 2 * i;
    ushort2 qp = *(ushort2*)(qraw + off);
    ushort2 kp = *(ushort2*)(kraw + off);
    float qr = bf2f(qp.x), qi = bf2f(qp.y);
    float kr = bf2f(kp.x), ki = bf2f(kp.y);
    ushort2 qo, ko;
    qo.x = f2bf(qr * cs - qi * sn); qo.y = f2bf(qr * sn + qi * cs);
    ko.x = f2bf(kr * cs - ki * sn); ko.y = f2bf(kr * sn + ki * cs);
    *(ushort2*)(qraw + off) = qo;
    *(ushort2*)(kraw + off) = ko;
}

// ---------------------------------------------------------------- flash attention
__global__ __launch_bounds__(256) void attn_kernel(
    const unsigned short* __restrict__ qb, const unsigned short* __restrict__ kb,
    const unsigned short* __restrict__ vt, unsigned short* __restrict__ ctx) {
    __shared__ __align__(16) unsigned short Ks[2][64 * 128];   // [key][dk]   2x16 KB
    __shared__ __align__(16) unsigned short Vs[2][128 * 64];   // [dk][key]   2x16 KB
    __shared__ __align__(16) unsigned short pbuf[4][16 * 68];  // stride 68: 2-way banks
    const int qt   = 31 - blockIdx.y;               // heavy tiles dispatched first
    const int u    = blockIdx.x;
    const int bh   = ((u & 7) << 2) | (u >> 3);     // same head -> same XCD (id%8)
    const int q0   = qt * 64;
    const int w    = threadIdx.x >> 6, lane = threadIdx.x & 63;
    const int lrow = lane & 15, quad = lane >> 4;
    const int qrow = q0 + w * 16;
    const float sc2 = 0.08838834764831845f * 1.4426950408889634f;  // DK^-.5 * log2e
    const short8 vone = {16256, 16256, 16256, 16256, 16256, 16256, 16256, 16256}; // bf16 1.0

    // Q A-frags (A[m=lane&15][k=quad*8+j], k-chunks of 32 over DK=128)
    short8 aq[4];
    const unsigned short* qbase = qb + ((size_t)bh * T_SEQ + qrow + lrow) * DK;
#pragma unroll
    for (int kk = 0; kk < 4; ++kk)
        aq[kk] = *(const short8*)(qbase + kk * 32 + quad * 8);

    f32x4 o[8];
#pragma unroll
    for (int d = 0; d < 8; ++d) o[d] = (f32x4){0.f, 0.f, 0.f, 0.f};
    f32x4 ol = (f32x4){0.f, 0.f, 0.f, 0.f};   // row sums of P (denominator)

    const unsigned short* kg0 = kb + (size_t)bh * T_SEQ * DK;
    const unsigned short* vg0 = vt + (size_t)bh * DK * T_SEQ;

    auto stage = [&](int kt, int sbuf) {
        const unsigned short* kg = kg0 + (size_t)kt * 64 * DK;
        const unsigned short* vg = vg0 + kt * 64;
        unsigned short* Kd = &Ks[sbuf][0];
        unsigned short* Vd = &Vs[sbuf][0];
#pragma unroll
        for (int j = 0; j < 4; ++j) {
            int c = (w * 4 + j) * 64 + lane;            // 0..1023
            int kr_ = c >> 4, kc = (c & 15) ^ (kr_ & 7);
            async_load16(kg + (size_t)kr_ * DK + kc * 8, Kd + c * 8);
            int vr = c >> 3, vc = (c & 7) ^ (vr & 7);
            async_load16(vg + (size_t)vr * T_SEQ + vc * 8, Vd + c * 8);
        }
    };

    stage(0, 0);
    for (int kt = 0; kt <= qt; ++kt) {
        __syncthreads();   // drains own vmcnt (incl. stage(kt)) then syncs waves
        if (kt < qt) stage(kt + 1, (kt + 1) & 1);
        const unsigned short* Kb = &Ks[kt & 1][0];
        const unsigned short* Vb = &Vs[kt & 1][0];

        // ---- S = Q K^T (16x64 per wave)
        f32x4 s[4];
#pragma unroll
        for (int nt = 0; nt < 4; ++nt) s[nt] = (f32x4){0.f, 0.f, 0.f, 0.f};
#pragma unroll
        for (int kk = 0; kk < 4; ++kk)
#pragma unroll
            for (int nt = 0; nt < 4; ++nt) {
                int row = nt * 16 + lrow;
                int kc = (kk * 4 + quad) ^ (row & 7);
                short8 bk = *(const short8*)(Kb + row * 128 + kc * 8);
                s[nt] = __builtin_amdgcn_mfma_f32_16x16x32_bf16(aq[kk], bk, s[nt], 0, 0, 0);
            }

        // ---- fixed-M softmax numerator: p = 2^(s*sc2 - 12); causal zero on diag
        const bool diag = (kt == qt);
        unsigned short* pb = &pbuf[w][0];
#pragma unroll
        for (int nt = 0; nt < 4; ++nt)
#pragma unroll
            for (int r = 0; r < 4; ++r) {
                float p = exp2f(fmaf(s[nt][r], sc2, -12.0f));
                if (diag && (nt * 16 + lrow > w * 16 + quad * 4 + r)) p = 0.f;
                pb[(quad * 4 + r) * 68 + nt * 16 + lrow] = f2bf(p);
            }
        __builtin_amdgcn_s_waitcnt(0xc07f);  // lgkmcnt(0): P writes visible
        short8 ap[2];
#pragma unroll
        for (int kk2 = 0; kk2 < 2; ++kk2)
            ap[kk2] = *(const short8*)(pb + lrow * 68 + kk2 * 32 + quad * 8);

        // ---- O += P V ; l += P @ ones
#pragma unroll
        for (int kk2 = 0; kk2 < 2; ++kk2)
            ol = __builtin_amdgcn_mfma_f32_16x16x32_bf16(ap[kk2], vone, ol, 0, 0, 0);
#pragma unroll
        for (int d = 0; d < 8; ++d)
#pragma unroll
            for (int kk2 = 0; kk2 < 2; ++kk2) {
                int row = d * 16 + lrow;
                int vc = (kk2 * 4 + quad) ^ (row & 7);
                short8 bv = *(const short8*)(Vb + row * 64 + vc * 8);
                o[d] = __builtin_amdgcn_mfma_f32_16x16x32_bf16(ap[kk2], bv, o[d], 0, 0, 0);
            }
    }

    // epilogue: ctx (b, t, h*DK+dk) bf16 ; divide by row sum (shift cancels)
    const int b = bh >> 4, h = bh & 15;
    float rl[4];
#pragma unroll
    for (int r = 0; r < 4; ++r) rl[r] = 1.0f / ol[r];
#pragma unroll
    for (int d = 0; d < 8; ++d)
#pragma unroll
        for (int r = 0; r < 4; ++r) {
            int row = qrow + quad * 4 + r;
            ctx[((size_t)(b * T_SEQ + row)) * DMODEL + h * DK + d * 16 + lrow] =
                f2bf(o[d][r] * rl[r]);
        }
}

// ---------------------------------------------------------------- launch
extern "C" void kernel_launch(void* const* d_in, const int* in_sizes, int n_in,
                              void* d_out, int out_size, void* d_ws, size_t ws_size,
                              hipStream_t stream) {
    const float* x     = (const float*)d_in[0];
    const float* freqs = (const float*)d_in[1];
    const float* Wqkv  = (const float*)d_in[2];
    const float* Wout  = (const float*)d_in[3];
    float* out = (float*)d_out;
    char* ws = (char*)d_ws;
    // workspace layout (96 MiB total); ctx aliases xb (dead after GEMM1)
    unsigned short* xb    = (unsigned short*)(ws);               // 16 MiB
    unsigned short* ctx   = (unsigned short*)(ws);               // 16 MiB (alias)
    unsigned short* wqkvT = (unsigned short*)(ws + 16777216);    // 24 MiB
    unsigned short* woutT = (unsigned short*)(ws + 41943040);    // 8 MiB
    unsigned short* qraw  = (unsigned short*)(ws + 50331648);    // 16 MiB
    unsigned short* kraw  = (unsigned short*)(ws + 67108864);    // 16 MiB
    unsigned short* vtb   = (unsigned short*)(ws + 83886080);    // 16 MiB

    cast_x_kernel<<<8192, 256, 0, stream>>>(x, xb, 2097152);
    wtrans_kernel<<<dim3(96, 32), 256, 0, stream>>>(Wqkv, wqkvT, DMODEL, NQKV);
    wtrans_kernel<<<dim3(32, 32), 256, 0, stream>>>(Wout, woutT, DMODEL, DMODEL);
    gemm8p_qkv_kernel<<<384, 512, 0, stream>>>(xb, wqkvT, qraw, kraw, vtb);
    rope_kernel<<<16384, 256, 0, stream>>>(qraw, kraw, freqs);
    attn_kernel<<<dim3(32, 32), 256, 0, stream>>>(qraw, kraw, vtb, ctx);
    gemm_bt_kernel<0><<<dim3(16, 32), 256, 0, stream>>>(
        ctx, woutT, out, nullptr, nullptr, nullptr, BATCH * T_SEQ, DMODEL, DMODEL);
}

// Round 4
// 384.550 us; speedup vs baseline: 1.0606x; 1.0606x over previous
//
#include <hip/hip_runtime.h>
#include <cstdint>

// Problem constants
#define BATCH   2
#define T_SEQ   2048
#define NH      16
#define DK      128
#define DMODEL  2048   // NH*DK
#define NQKV    6144   // 3*DMODEL

using short8 = __attribute__((ext_vector_type(8))) short;   // 8 bf16 (4 VGPRs)
using f32x4  = __attribute__((ext_vector_type(4))) float;   // 16x16 MFMA C/D
using f32x16 = __attribute__((ext_vector_type(16))) float;  // 32x32 MFMA C/D

__device__ __forceinline__ float bf2f(unsigned short u) {
    union { float f; uint32_t i; } x; x.i = ((uint32_t)u) << 16; return x.f;
}
__device__ __forceinline__ unsigned short f2bf(float f) {
    union { float f; uint32_t i; } x; x.f = f;
    uint32_t r = x.i + 0x7fffu + ((x.i >> 16) & 1u);   // RNE (no NaN inputs here)
    return (unsigned short)(r >> 16);
}

// async global->LDS, 16B per lane. LDS dest = wave-uniform base + lane*16 (m104/m108).
__device__ __forceinline__ void async_load16(const unsigned short* g, unsigned short* l) {
    __builtin_amdgcn_global_load_lds(
        (const __attribute__((address_space(1))) unsigned int*)g,
        (__attribute__((address_space(3))) unsigned int*)l,
        16, 0, 0);
}

// ---------------------------------------------------------------- prep kernels

__global__ void cast_x_kernel(const float* __restrict__ x,
                              unsigned short* __restrict__ xb, int n4) {
    int i = blockIdx.x * 256 + threadIdx.x;
    if (i >= n4) return;
    float4 v = ((const float4*)x)[i];
    ushort4 o;
    o.x = f2bf(v.x); o.y = f2bf(v.y); o.z = f2bf(v.z); o.w = f2bf(v.w);
    ((ushort4*)xb)[i] = o;
}

// W (K,N) fp32 row-major -> WT (N,K) bf16 row-major (for gemm_bt B-frag reads)
__global__ void wtrans_kernel(const float* __restrict__ W,
                              unsigned short* __restrict__ WT, int K, int N) {
    __shared__ unsigned short tile[64][65];  // +1 pad
    int k0 = blockIdx.y * 64, n0 = blockIdx.x * 64;
    for (int it = 0; it < 16; ++it) {
        int idx = it * 256 + threadIdx.x;
        int r = idx >> 6, c = idx & 63;                       // r: k-row, c: n-col
        tile[r][c] = f2bf(W[(size_t)(k0 + r) * N + n0 + c]);  // coalesced in n
    }
    __syncthreads();
    for (int it = 0; it < 16; ++it) {
        int idx = it * 256 + threadIdx.x;
        int r = idx >> 6, c = idx & 63;                       // r: n-row of WT, c: k-col
        WT[(size_t)(n0 + r) * K + k0 + c] = tile[c][r];       // coalesced in k
    }
}

// ---------------------------------------------------------------- GEMM (legacy 128x128, used for GEMM2)
template <int MODE>
__global__ __launch_bounds__(256) void gemm_bt_kernel(
    const unsigned short* __restrict__ A, const unsigned short* __restrict__ BT,
    float* __restrict__ Cout,
    unsigned short* __restrict__ qraw, unsigned short* __restrict__ kraw,
    unsigned short* __restrict__ vtb,
    int M, int N, int K) {
    __shared__ __align__(16) unsigned short As[128 * 64];
    __shared__ __align__(16) unsigned short Bs[128 * 64];
    const int tid = threadIdx.x;
    const int w = tid >> 6, lane = tid & 63;
    const int l31 = lane & 31, lhi = lane >> 5;
    const int m0 = blockIdx.y * 128, n0 = blockIdx.x * 128;
    const int wm = (w & 1) * 64, wn = (w >> 1) * 64;

    f32x16 acc[2][2];
#pragma unroll
    for (int a = 0; a < 2; ++a)
#pragma unroll
        for (int b = 0; b < 2; ++b)
#pragma unroll
            for (int r = 0; r < 16; ++r) acc[a][b][r] = 0.f;

    for (int k0 = 0; k0 < K; k0 += 64) {
#pragma unroll
        for (int j = 0; j < 4; ++j) {
            int c   = (w * 4 + j) * 64 + lane;   // chunk id 0..1023
            int row = c >> 3;
            int kcg = (c & 7) ^ (row & 7);       // swizzled global 16B column-chunk
            async_load16(A  + (size_t)(m0 + row) * K + k0 + kcg * 8,
                         As + (size_t)(w * 4 + j) * 64 * 8);
            async_load16(BT + (size_t)(n0 + row) * K + k0 + kcg * 8,
                         Bs + (size_t)(w * 4 + j) * 64 * 8);
        }
        __syncthreads();   // drains vmcnt for global_load_lds
#pragma unroll
        for (int ks = 0; ks < 4; ++ks) {         // 4 k-steps of 16
            short8 af[2], bfr[2];
#pragma unroll
            for (int mt = 0; mt < 2; ++mt) {
                int row = wm + mt * 32 + l31;
                int kcs = (ks * 2 + lhi) ^ (row & 7);
                af[mt] = *(const short8*)(As + row * 64 + kcs * 8);
            }
#pragma unroll
            for (int nt = 0; nt < 2; ++nt) {
                int row = wn + nt * 32 + l31;
                int kcs = (ks * 2 + lhi) ^ (row & 7);
                bfr[nt] = *(const short8*)(Bs + row * 64 + kcs * 8);
            }
#pragma unroll
            for (int mt = 0; mt < 2; ++mt)
#pragma unroll
                for (int nt = 0; nt < 2; ++nt)
                    acc[mt][nt] = __builtin_amdgcn_mfma_f32_32x32x16_bf16(
                        af[mt], bfr[nt], acc[mt][nt], 0, 0, 0);
        }
        __syncthreads();
    }

    if (MODE == 0) {
#pragma unroll
        for (int mt = 0; mt < 2; ++mt)
#pragma unroll
            for (int nt = 0; nt < 2; ++nt)
#pragma unroll
                for (int r = 0; r < 16; ++r) {
                    int row = m0 + wm + mt * 32 + (r & 3) + 8 * (r >> 2) + 4 * lhi;
                    int col = n0 + wn + nt * 32 + l31;
                    Cout[(size_t)row * N + col] = acc[mt][nt][r];
                }
    }
}

// ---------------------------------------------------------------- GEMM1: 256x256 8-phase
// Round-4 rev: round-2's exact phase/read structure (130us, ZERO bank
// conflicts — the 16x16 l15-span read pattern is the only measured
// conflict-free one; 32x32 l31-span costs 4 conflict-cy/read, r3 post-mortem)
// PLUS: (a) XCD remap to 4-row x 12-col regions col-major-within (round-1/2's
// 2x24 slab streamed all 24MB of B through every XCD L2: FETCH 177MB vs
// legacy 90MB); (b) RoPE fused into the epilogue (kills the rope kernel's
// 64MB round-trip; dk-parity == lane-parity so partner = __shfl_xor(v,1)).
// Staging schedule & vmcnt ledger IDENTICAL to rounds 1-3 (verified 3x):
//   P0:A1h1(t+1) P1:B1h1(t+1) P2:A0h0(t+2) P3:B0h0(t+2) [vm4 -> buf1(t+1) landed]
//   P4:A0h1(t+2) P5:B0h1(t+2) P6:A1h0(t+3) P7:B1h0(t+3) [vm4 -> buf0(t+2) landed]
#define G1_K 2048
#define G1_N 6144

__global__ __launch_bounds__(512, 2) void gemm8p_qkv_kernel(
    const unsigned short* __restrict__ A, const unsigned short* __restrict__ BT,
    const float* __restrict__ freqs,
    unsigned short* __restrict__ qraw, unsigned short* __restrict__ kraw,
    unsigned short* __restrict__ vtb) {
    __shared__ __align__(16) unsigned short As[2][256 * 64];   // 64 KiB
    __shared__ __align__(16) unsigned short Bs[2][256 * 64];   // 64 KiB

    const int tid = threadIdx.x;
    const int w = tid >> 6, lane = tid & 63;
    const int l15 = lane & 15, quad = lane >> 4, l7 = lane & 7;
    const int wm = (w & 1) * 128, wn = (w >> 1) * 64;

    // XCD-aware 2D chunking: dispatch XCD = id%8 (round-robin, m09). Each XCD
    // owns a 4-row x 12-col region of the 16x24 tile grid, walked col-major so
    // the ~32 concurrent blocks per XCD share B-panels 4-ways and keep the 4
    // A-panels warm. Bijective: xcd 0-7, j 0-47 -> by 0-15, bx 0-23.
    const int id = blockIdx.x;
    const int xcd = id & 7, j = id >> 3;
    const int by = (xcd >> 1) * 4 + (j & 3);
    const int bx = (xcd & 1) * 12 + (j >> 2);
    const int m0 = by * 256, n0 = bx * 256;

    // staging geometry: 512 thr x 16B = 64 rows/issue; global chunk pre-swizzle
    const int r64 = tid >> 3;                    // row within 64-row issue
    const int csw = (tid & 7) ^ (r64 & 7);       // swizzled source 16B chunk

    auto stageA = [&](int buf, int kt, int h) {  // A-half h = rows bit6==h
#pragma unroll
        for (int jj = 0; jj < 2; ++jj) {
            const int rg = h * 64 + jj * 128 + r64;
            async_load16(A + (size_t)(m0 + rg) * G1_K + kt * 64 + csw * 8,
                         &As[buf][(h * 64 + jj * 128 + w * 8) << 6]);
        }
    };
    auto stageB = [&](int buf, int kt, int h) {  // B-half h = rows bit5==h
#pragma unroll
        for (int jj = 0; jj < 2; ++jj) {
            const int rbw = jj * 128 + ((w >> 2) << 6) + h * 32 + ((w & 3) << 3);
            const int rg  = rbw + (lane >> 3);
            async_load16(BT + (size_t)(n0 + rg) * G1_K + kt * 64 + csw * 8,
                         &Bs[buf][rbw << 6]);
        }
    };

    f32x4 acc[8][4];
#pragma unroll
    for (int i = 0; i < 8; ++i)
#pragma unroll
        for (int jj = 0; jj < 4; ++jj) acc[i][jj] = (f32x4){0.f, 0.f, 0.f, 0.f};

#define LOADA(BUF, H)                                                           \
  _Pragma("unroll") for (int mt = 0; mt < 4; ++mt)                              \
    _Pragma("unroll") for (int ks = 0; ks < 2; ++ks)                            \
      paf[mt][ks] = *(const short8*)(&As[BUF][((wm + (H)*64 + mt*16 + l15)      \
          << 6) + (((ks*4 + quad) ^ l7) << 3)]);

#define LOADB(BUF, H, DST)                                                      \
  _Pragma("unroll") for (int nt = 0; nt < 2; ++nt)                              \
    _Pragma("unroll") for (int ks = 0; ks < 2; ++ks)                            \
      DST[nt][ks] = *(const short8*)(&Bs[BUF][((wn + (H)*32 + nt*16 + l15)      \
          << 6) + (((ks*4 + quad) ^ l7) << 3)]);

#define MFMAQ(QM, QN, PB)                                                       \
  __builtin_amdgcn_s_setprio(1);                                                \
  _Pragma("unroll") for (int mt = 0; mt < 4; ++mt)                              \
    _Pragma("unroll") for (int nt = 0; nt < 2; ++nt)                            \
      _Pragma("unroll") for (int ks = 0; ks < 2; ++ks)                          \
        acc[(QM)*4 + mt][(QN)*2 + nt] =                                         \
            __builtin_amdgcn_mfma_f32_16x16x32_bf16(                            \
                paf[mt][ks], PB[nt][ks], acc[(QM)*4 + mt][(QN)*2 + nt],         \
                0, 0, 0);                                                       \
  __builtin_amdgcn_s_setprio(0);

#define LGK0 asm volatile("s_waitcnt lgkmcnt(0)" ::: "memory");                 \
             __builtin_amdgcn_sched_barrier(0)
#define LGK8 asm volatile("s_waitcnt lgkmcnt(8)" ::: "memory")
#define BAR  __builtin_amdgcn_s_barrier()
#define VM4  asm volatile("s_waitcnt vmcnt(4)" ::: "memory")
#define VM0  asm volatile("s_waitcnt vmcnt(0)" ::: "memory")

    // prologue: tile0 fully + A0,B0 of tile1; retire tile0, keep 4 loads in flight
    stageA(0, 0, 0); stageB(0, 0, 0); stageA(0, 0, 1); stageB(0, 0, 1);
    stageA(1, 1, 0); stageB(1, 1, 0);
    VM4;
    BAR;

    const int NI = G1_K / 128;   // 16 iterations, 2 K-tiles each
    for (int it = 0; it < NI; ++it) {
        const int t1 = 2 * it + 1;
        const bool last = (it == NI - 1);
        short8 paf[4][2], pbf0[2][2], pbf1[2][2];
        // ---------------- buffer 0 = tile 2it, Gray order (0,0)(0,1)(1,1)(1,0)
        // P0: load A-h0 + B-h0
        LOADA(0, 0) LOADB(0, 0, pbf0)
        stageA(1, t1, 1);
        LGK8; BAR; LGK0;
        MFMAQ(0, 0, pbf0)
        BAR;
        // P1: load B-h1 (A cached)
        LOADB(0, 1, pbf1)
        stageB(1, t1, 1);
        BAR; LGK0;
        MFMAQ(0, 1, pbf1)
        BAR;
        // P2: load A-h1 (B-h1 cached)
        LOADA(0, 1)
        if (!last) stageA(0, t1 + 1, 0);
        BAR; LGK0;
        MFMAQ(1, 1, pbf1)
        BAR;
        // P3: no LDS reads (A-h1 + B-h0 cached)
        if (!last) stageB(0, t1 + 1, 0);
        BAR;
        MFMAQ(1, 0, pbf0)
        if (last) { VM0; } else { VM4; }   // buf1(t+1) fully landed
        BAR;
        // ---------------- buffer 1 = tile 2it+1
        // P4
        LOADA(1, 0) LOADB(1, 0, pbf0)
        if (!last) stageA(0, t1 + 1, 1);
        LGK8; BAR; LGK0;
        MFMAQ(0, 0, pbf0)
        BAR;
        // P5
        LOADB(1, 1, pbf1)
        if (!last) stageB(0, t1 + 1, 1);
        BAR; LGK0;
        MFMAQ(0, 1, pbf1)
        BAR;
        // P6
        LOADA(1, 1)
        if (!last) stageA(1, t1 + 2, 0);
        BAR; LGK0;
        MFMAQ(1, 1, pbf1)
        BAR;
        // P7
        if (!last) stageB(1, t1 + 2, 0);
        BAR;
        MFMAQ(1, 0, pbf0)
        if (!last) { VM4; }                // buf0(t+2) fully landed
        BAR;
    }

    // epilogue: scatter qkv with FUSED RoPE on q/k.  C/D 16x16 layout:
    // col=lane&15, row=quad*4+reg (m89). qkv col -> head h = col/384;
    // [0,128) q, [128,256) k, [256,384) v; 16-col tiles never straddle.
    // RoPE: dk parity == l15 parity (colb is even), rotate partner is the
    // same t at dk^1 -> __shfl_xor(v,1). even: v*cs - p*sn; odd: v*cs + p*sn.
    // Applied on fp32 acc before bf16 store (better than standalone kernel).
#pragma unroll
    for (int i8 = 0; i8 < 8; ++i8) {
        const int grow0 = m0 + wm + i8 * 16 + quad * 4;   // + r
        const int bi = grow0 >> 11;
        const int tb = grow0 & (T_SEQ - 1);
#pragma unroll
        for (int j4 = 0; j4 < 4; ++j4) {
            const int gcol = n0 + wn + j4 * 16 + l15;
            const int h   = gcol / 384;
            const int r3  = gcol - h * 384;
            const int sec = r3 >> 7;
            const int dk  = r3 & 127;
            if (sec < 2) {
                const float sgn = (dk & 1) ? 1.f : -1.f;
                const float* fp = freqs +
                    ((size_t)(bi * T_SEQ + tb)) * 64 + (dk >> 1);
                unsigned short* dst = (sec == 0 ? qraw : kraw) +
                    ((size_t)(bi * NH + h) * T_SEQ + tb) * DK + dk;
#pragma unroll
                for (int r = 0; r < 4; ++r) {
                    float v = acc[i8][j4][r];
                    float p = __shfl_xor(v, 1);
                    float f = fp[(size_t)r * 64];
                    float cs = __cosf(f), sn = __sinf(f);
                    dst[(size_t)r * DK] = f2bf(fmaf(v, cs, sgn * (p * sn)));
                }
            } else {
                // V stored transposed (B,H,DK,T): 4 regs = 4 consecutive t
                unsigned short* dst = vtb +
                    ((size_t)(bi * NH + h) * DK + dk) * T_SEQ + tb;
                ushort4 pk;
                pk.x = f2bf(acc[i8][j4][0]); pk.y = f2bf(acc[i8][j4][1]);
                pk.z = f2bf(acc[i8][j4][2]); pk.w = f2bf(acc[i8][j4][3]);
                *(ushort4*)dst = pk;
            }
        }
    }
#undef LOADA
#undef LOADB
#undef MFMAQ
#undef LGK0
#undef LGK8
#undef BAR
#undef VM4
#undef VM0
}

// ---------------------------------------------------------------- flash attention
__global__ __launch_bounds__(256) void attn_kernel(
    const unsigned short* __restrict__ qb, const unsigned short* __restrict__ kb,
    const unsigned short* __restrict__ vt, unsigned short* __restrict__ ctx) {
    __shared__ __align__(16) unsigned short Ks[2][64 * 128];   // [key][dk]   2x16 KB
    __shared__ __align__(16) unsigned short Vs[2][128 * 64];   // [dk][key]   2x16 KB
    __shared__ __align__(16) unsigned short pbuf[4][16 * 68];  // stride 68: 2-way banks
    const int qt   = 31 - blockIdx.y;               // heavy tiles dispatched first
    const int u    = blockIdx.x;
    const int bh   = ((u & 7) << 2) | (u >> 3);     // same head -> same XCD (id%8)
    const int q0   = qt * 64;
    const int w    = threadIdx.x >> 6, lane = threadIdx.x & 63;
    const int lrow = lane & 15, quad = lane >> 4;
    const int qrow = q0 + w * 16;
    const float sc2 = 0.08838834764831845f * 1.4426950408889634f;  // DK^-.5 * log2e
    const short8 vone = {16256, 16256, 16256, 16256, 16256, 16256, 16256, 16256}; // bf16 1.0

    // Q A-frags (A[m=lane&15][k=quad*8+j], k-chunks of 32 over DK=128)
    short8 aq[4];
    const unsigned short* qbase = qb + ((size_t)bh * T_SEQ + qrow + lrow) * DK;
#pragma unroll
    for (int kk = 0; kk < 4; ++kk)
        aq[kk] = *(const short8*)(qbase + kk * 32 + quad * 8);

    f32x4 o[8];
#pragma unroll
    for (int d = 0; d < 8; ++d) o[d] = (f32x4){0.f, 0.f, 0.f, 0.f};
    f32x4 ol = (f32x4){0.f, 0.f, 0.f, 0.f};   // row sums of P (denominator)

    const unsigned short* kg0 = kb + (size_t)bh * T_SEQ * DK;
    const unsigned short* vg0 = vt + (size_t)bh * DK * T_SEQ;

    auto stage = [&](int kt, int sbuf) {
        const unsigned short* kg = kg0 + (size_t)kt * 64 * DK;
        const unsigned short* vg = vg0 + kt * 64;
        unsigned short* Kd = &Ks[sbuf][0];
        unsigned short* Vd = &Vs[sbuf][0];
#pragma unroll
        for (int j = 0; j < 4; ++j) {
            int c = (w * 4 + j) * 64 + lane;            // 0..1023
            int kr_ = c >> 4, kc = (c & 15) ^ (kr_ & 7);
            async_load16(kg + (size_t)kr_ * DK + kc * 8, Kd + c * 8);
            int vr = c >> 3, vc = (c & 7) ^ (vr & 7);
            async_load16(vg + (size_t)vr * T_SEQ + vc * 8, Vd + c * 8);
        }
    };

    stage(0, 0);
    for (int kt = 0; kt <= qt; ++kt) {
        __syncthreads();   // drains own vmcnt (incl. stage(kt)) then syncs waves
        if (kt < qt) stage(kt + 1, (kt + 1) & 1);
        const unsigned short* Kb = &Ks[kt & 1][0];
        const unsigned short* Vb = &Vs[kt & 1][0];

        // ---- S = Q K^T (16x64 per wave)
        f32x4 s[4];
#pragma unroll
        for (int nt = 0; nt < 4; ++nt) s[nt] = (f32x4){0.f, 0.f, 0.f, 0.f};
#pragma unroll
        for (int kk = 0; kk < 4; ++kk)
#pragma unroll
            for (int nt = 0; nt < 4; ++nt) {
                int row = nt * 16 + lrow;
                int kc = (kk * 4 + quad) ^ (row & 7);
                short8 bk = *(const short8*)(Kb + row * 128 + kc * 8);
                s[nt] = __builtin_amdgcn_mfma_f32_16x16x32_bf16(aq[kk], bk, s[nt], 0, 0, 0);
            }

        // ---- fixed-M softmax numerator: p = 2^(s*sc2 - 12); causal zero on diag
        const bool diag = (kt == qt);
        unsigned short* pb = &pbuf[w][0];
#pragma unroll
        for (int nt = 0; nt < 4; ++nt)
#pragma unroll
            for (int r = 0; r < 4; ++r) {
                float p = exp2f(fmaf(s[nt][r], sc2, -12.0f));
                if (diag && (nt * 16 + lrow > w * 16 + quad * 4 + r)) p = 0.f;
                pb[(quad * 4 + r) * 68 + nt * 16 + lrow] = f2bf(p);
            }
        __builtin_amdgcn_s_waitcnt(0xc07f);  // lgkmcnt(0): P writes visible
        short8 ap[2];
#pragma unroll
        for (int kk2 = 0; kk2 < 2; ++kk2)
            ap[kk2] = *(const short8*)(pb + lrow * 68 + kk2 * 32 + quad * 8);

        // ---- O += P V ; l += P @ ones
#pragma unroll
        for (int kk2 = 0; kk2 < 2; ++kk2)
            ol = __builtin_amdgcn_mfma_f32_16x16x32_bf16(ap[kk2], vone, ol, 0, 0, 0);
#pragma unroll
        for (int d = 0; d < 8; ++d)
#pragma unroll
            for (int kk2 = 0; kk2 < 2; ++kk2) {
                int row = d * 16 + lrow;
                int vc = (kk2 * 4 + quad) ^ (row & 7);
                short8 bv = *(const short8*)(Vb + row * 64 + vc * 8);
                o[d] = __builtin_amdgcn_mfma_f32_16x16x32_bf16(ap[kk2], bv, o[d], 0, 0, 0);
            }
    }

    // epilogue: ctx (b, t, h*DK+dk) bf16 ; divide by row sum (shift cancels)
    const int b = bh >> 4, h = bh & 15;
    float rl[4];
#pragma unroll
    for (int r = 0; r < 4; ++r) rl[r] = 1.0f / ol[r];
#pragma unroll
    for (int d = 0; d < 8; ++d)
#pragma unroll
        for (int r = 0; r < 4; ++r) {
            int row = qrow + quad * 4 + r;
            ctx[((size_t)(b * T_SEQ + row)) * DMODEL + h * DK + d * 16 + lrow] =
                f2bf(o[d][r] * rl[r]);
        }
}

// ---------------------------------------------------------------- launch
extern "C" void kernel_launch(void* const* d_in, const int* in_sizes, int n_in,
                              void* d_out, int out_size, void* d_ws, size_t ws_size,
                              hipStream_t stream) {
    const float* x     = (const float*)d_in[0];
    const float* freqs = (const float*)d_in[1];
    const float* Wqkv  = (const float*)d_in[2];
    const float* Wout  = (const float*)d_in[3];
    float* out = (float*)d_out;
    char* ws = (char*)d_ws;
    // workspace layout (96 MiB total); ctx aliases xb (dead after GEMM1)
    unsigned short* xb    = (unsigned short*)(ws);               // 16 MiB
    unsigned short* ctx   = (unsigned short*)(ws);               // 16 MiB (alias)
    unsigned short* wqkvT = (unsigned short*)(ws + 16777216);    // 24 MiB
    unsigned short* woutT = (unsigned short*)(ws + 41943040);    // 8 MiB
    unsigned short* qraw  = (unsigned short*)(ws + 50331648);    // 16 MiB
    unsigned short* kraw  = (unsigned short*)(ws + 67108864);    // 16 MiB
    unsigned short* vtb   = (unsigned short*)(ws + 83886080);    // 16 MiB

    cast_x_kernel<<<8192, 256, 0, stream>>>(x, xb, 2097152);
    wtrans_kernel<<<dim3(96, 32), 256, 0, stream>>>(Wqkv, wqkvT, DMODEL, NQKV);
    wtrans_kernel<<<dim3(32, 32), 256, 0, stream>>>(Wout, woutT, DMODEL, DMODEL);
    gemm8p_qkv_kernel<<<384, 512, 0, stream>>>(xb, wqkvT, freqs, qraw, kraw, vtb);
    attn_kernel<<<dim3(32, 32), 256, 0, stream>>>(qraw, kraw, vtb, ctx);
    gemm_bt_kernel<0><<<dim3(16, 32), 256, 0, stream>>>(
        ctx, woutT, out, nullptr, nullptr, nullptr, BATCH * T_SEQ, DMODEL, DMODEL);
}

// Round 5
// 382.599 us; speedup vs baseline: 1.0660x; 1.0051x over previous
//
#include <hip/hip_runtime.h>
#include <cstdint>

// Problem constants
#define BATCH   2
#define T_SEQ   2048
#define NH      16
#define DK      128
#define DMODEL  2048   // NH*DK
#define NQKV    6144   // 3*DMODEL

using short8 = __attribute__((ext_vector_type(8))) short;   // 8 bf16 (4 VGPRs)
using f32x4  = __attribute__((ext_vector_type(4))) float;   // 16x16 MFMA C/D
using f32x16 = __attribute__((ext_vector_type(16))) float;  // 32x32 MFMA C/D

__device__ __forceinline__ float bf2f(unsigned short u) {
    union { float f; uint32_t i; } x; x.i = ((uint32_t)u) << 16; return x.f;
}
__device__ __forceinline__ unsigned short f2bf(float f) {
    union { float f; uint32_t i; } x; x.f = f;
    uint32_t r = x.i + 0x7fffu + ((x.i >> 16) & 1u);   // RNE (no NaN inputs here)
    return (unsigned short)(r >> 16);
}

// async global->LDS, 16B per lane. LDS dest = wave-uniform base + lane*16 (m104/m108).
__device__ __forceinline__ void async_load16(const unsigned short* g, unsigned short* l) {
    __builtin_amdgcn_global_load_lds(
        (const __attribute__((address_space(1))) unsigned int*)g,
        (__attribute__((address_space(3))) unsigned int*)l,
        16, 0, 0);
}

// ---------------------------------------------------------------- prep kernels

__global__ void cast_x_kernel(const float* __restrict__ x,
                              unsigned short* __restrict__ xb, int n4) {
    int i = blockIdx.x * 256 + threadIdx.x;
    if (i >= n4) return;
    float4 v = ((const float4*)x)[i];
    ushort4 o;
    o.x = f2bf(v.x); o.y = f2bf(v.y); o.z = f2bf(v.z); o.w = f2bf(v.w);
    ((ushort4*)xb)[i] = o;
}

// W (K,N) fp32 row-major -> WT (N,K) bf16 row-major (for gemm_bt B-frag reads)
__global__ void wtrans_kernel(const float* __restrict__ W,
                              unsigned short* __restrict__ WT, int K, int N) {
    __shared__ unsigned short tile[64][65];  // +1 pad
    int k0 = blockIdx.y * 64, n0 = blockIdx.x * 64;
    for (int it = 0; it < 16; ++it) {
        int idx = it * 256 + threadIdx.x;
        int r = idx >> 6, c = idx & 63;                       // r: k-row, c: n-col
        tile[r][c] = f2bf(W[(size_t)(k0 + r) * N + n0 + c]);  // coalesced in n
    }
    __syncthreads();
    for (int it = 0; it < 16; ++it) {
        int idx = it * 256 + threadIdx.x;
        int r = idx >> 6, c = idx & 63;                       // r: n-row of WT, c: k-col
        WT[(size_t)(n0 + r) * K + k0 + c] = tile[c][r];       // coalesced in k
    }
}

// ---------------------------------------------------------------- GEMM
// C(M,N) = A(M,K)bf16 @ BT(N,K)bf16^T.  128x128 tile, BK=64, 4 waves in 2x2,
// each wave 64x64 via 2x2 of v_mfma_f32_32x32x16_bf16. 32 KiB LDS -> 3
// blocks/CU co-resident (the implicit-overlap mechanism, m114) — measured
// faster than every 1-block/CU 8-phase variant tried in rounds 1-4.
//
// Bank-conflict fix (round-5): the old slot XOR `chunk ^ (row&7)` depends
// only on lane&7 within a stride-8 lane group {l,l+8,l+16,l+24,...}, giving
// a 4-way conflict on every ds_read_b128 (measured 4.0 extra cy/read =
// SQ_LDS_BANK_CONFLICT 1.26e7, rounds 0/3; the quad-varying 16x16 pattern
// measured 0). New involution adds row bits 3,4:
//   g(row) = (row&7) ^ ((row>>2)&6)
// Within a stride-8 group l31>>3 = 0..3 -> XOR {0,2,4,6} -> 4 distinct slots;
// lhi bit0 disambiguates halves -> 8 distinct 16B slots per 8-lane cycle.
// Applied identically on the staging SOURCE chunk (linear LDS dest, rule #21)
// and on A/B fragment reads. Per-8-lane-group source coverage is still a
// full contiguous 128B row -> global coalescing preserved.
// A/B operand layout: elem[m = lane&31][k = (lane>>5)*8 + j]; C/D layout
// (m74/m101): col = lane&31, row = (reg&3) + 8*(reg>>2) + 4*(lane>>5).
// MODE 0: fp32 row-major out.  MODE 1: scatter-to-q/k/(V^T) epilogue for GEMM1.
template <int MODE>
__global__ __launch_bounds__(256) void gemm_bt_kernel(
    const unsigned short* __restrict__ A, const unsigned short* __restrict__ BT,
    float* __restrict__ Cout,
    unsigned short* __restrict__ qraw, unsigned short* __restrict__ kraw,
    unsigned short* __restrict__ vtb,
    int M, int N, int K) {
    __shared__ __align__(16) unsigned short As[128 * 64];
    __shared__ __align__(16) unsigned short Bs[128 * 64];
    const int tid = threadIdx.x;
    const int w = tid >> 6, lane = tid & 63;
    const int l31 = lane & 31, lhi = lane >> 5;
    const int m0 = blockIdx.y * 128, n0 = blockIdx.x * 128;
    const int wm = (w & 1) * 64, wn = (w >> 1) * 64;

    f32x16 acc[2][2];
#pragma unroll
    for (int a = 0; a < 2; ++a)
#pragma unroll
        for (int b = 0; b < 2; ++b)
#pragma unroll
            for (int r = 0; r < 16; ++r) acc[a][b][r] = 0.f;

    // read-side swizzle term is wave-invariant: row = (wm|wn)+mt*32+l31 and
    // wm/wn/mt*32 only touch bits >=5, so g(row) = (l31&7) ^ ((l31>>2)&6)
    const int gsw = (l31 & 7) ^ ((l31 >> 2) & 6);

    for (int k0 = 0; k0 < K; k0 += 64) {
#pragma unroll
        for (int j = 0; j < 4; ++j) {
            int c   = (w * 4 + j) * 64 + lane;   // chunk id 0..1023
            int row = c >> 3;
            int kcg = (c & 7) ^ (row & 7) ^ ((row >> 2) & 6);  // swizzled source chunk
            async_load16(A  + (size_t)(m0 + row) * K + k0 + kcg * 8,
                         As + (size_t)(w * 4 + j) * 64 * 8);
            async_load16(BT + (size_t)(n0 + row) * K + k0 + kcg * 8,
                         Bs + (size_t)(w * 4 + j) * 64 * 8);
        }
        __syncthreads();   // drains vmcnt for global_load_lds
#pragma unroll
        for (int ks = 0; ks < 4; ++ks) {         // 4 k-steps of 16
            short8 af[2], bfr[2];
#pragma unroll
            for (int mt = 0; mt < 2; ++mt) {
                int row = wm + mt * 32 + l31;
                int kcs = (ks * 2 + lhi) ^ gsw;
                af[mt] = *(const short8*)(As + row * 64 + kcs * 8);
            }
#pragma unroll
            for (int nt = 0; nt < 2; ++nt) {
                int row = wn + nt * 32 + l31;
                int kcs = (ks * 2 + lhi) ^ gsw;
                bfr[nt] = *(const short8*)(Bs + row * 64 + kcs * 8);
            }
#pragma unroll
            for (int mt = 0; mt < 2; ++mt)
#pragma unroll
                for (int nt = 0; nt < 2; ++nt)
                    acc[mt][nt] = __builtin_amdgcn_mfma_f32_32x32x16_bf16(
                        af[mt], bfr[nt], acc[mt][nt], 0, 0, 0);
        }
        __syncthreads();
    }

    if (MODE == 0) {
#pragma unroll
        for (int mt = 0; mt < 2; ++mt)
#pragma unroll
            for (int nt = 0; nt < 2; ++nt)
#pragma unroll
                for (int r = 0; r < 16; ++r) {
                    int row = m0 + wm + mt * 32 + (r & 3) + 8 * (r >> 2) + 4 * lhi;
                    int col = n0 + wn + nt * 32 + l31;
                    Cout[(size_t)row * N + col] = acc[mt][nt][r];
                }
    } else {
        // qkv column -> head h = col/384; within-head: [0,128) q, [128,256) k,
        // [256,384) v. 32-col tiles never straddle sections (128 % 32 == 0).
#pragma unroll
        for (int mt = 0; mt < 2; ++mt) {
            int trowb = m0 + wm + mt * 32;      // 32-row tile, within one batch
            int bi = trowb >> 11;
            int tb = trowb & (T_SEQ - 1);
#pragma unroll
            for (int nt = 0; nt < 2; ++nt) {
                int colb = n0 + wn + nt * 32;
                int h    = colb / 384;
                int r3   = colb - h * 384;
                int sec  = r3 >> 7;
                int dk   = (r3 & 127) + l31;
                if (sec < 2) {
                    unsigned short* dst = (sec == 0 ? qraw : kraw) +
                        ((size_t)(bi * NH + h) * T_SEQ + tb) * DK + dk;
#pragma unroll
                    for (int r = 0; r < 16; ++r) {
                        int t = (r & 3) + 8 * (r >> 2) + 4 * lhi;
                        dst[(size_t)t * DK] = f2bf(acc[mt][nt][r]);
                    }
                } else {
                    // V stored transposed (B,H,DK,T): regs 4g..4g+3 are 4
                    // consecutive t -> one 8B store per group
                    unsigned short* dst =
                        vtb + ((size_t)(bi * NH + h) * DK + dk) * T_SEQ + tb;
#pragma unroll
                    for (int g = 0; g < 4; ++g) {
                        ushort4 p;
                        p.x = f2bf(acc[mt][nt][4 * g + 0]);
                        p.y = f2bf(acc[mt][nt][4 * g + 1]);
                        p.z = f2bf(acc[mt][nt][4 * g + 2]);
                        p.w = f2bf(acc[mt][nt][4 * g + 3]);
                        *(ushort4*)(dst + 8 * g + 4 * lhi) = p;
                    }
                }
            }
        }
    }
}

// ---------------------------------------------------------------- RoPE (in place)
__global__ void rope_kernel(unsigned short* __restrict__ qraw,
                            unsigned short* __restrict__ kraw,
                            const float* __restrict__ freqs) {
    int linear = blockIdx.x * 256 + threadIdx.x;   // ((b*NH+h)*T + t)*64 + i
    int i  = linear & 63;
    int t  = (linear >> 6) & (T_SEQ - 1);
    int bh = linear >> 17;
    int b  = bh >> 4;
    float f  = freqs[((size_t)b * T_SEQ + t) * 64 + i];
    float cs = __cosf(f), sn = __sinf(f);
    size_t off = ((size_t)bh * T_SEQ + t) * DK + 2 * i;
    ushort2 qp = *(ushort2*)(qraw + off);
    ushort2 kp = *(ushort2*)(kraw + off);
    float qr = bf2f(qp.x), qi = bf2f(qp.y);
    float kr = bf2f(kp.x), ki = bf2f(kp.y);
    ushort2 qo, ko;
    qo.x = f2bf(qr * cs - qi * sn); qo.y = f2bf(qr * sn + qi * cs);
    ko.x = f2bf(kr * cs - ki * sn); ko.y = f2bf(kr * sn + ki * cs);
    *(ushort2*)(qraw + off) = qo;
    *(ushort2*)(kraw + off) = ko;
}

// ---------------------------------------------------------------- flash attention
// Grid (32,32): qt = 31-blockIdx.y (heavy first), bh XCD-swizzled from blockIdx.x
// so each head's K/V stays in one XCD's L2. 4 waves/block, wave owns 16 q-rows.
// Ping-pong K/V LDS staging (ONE barrier/tile). Fixed-M softmax (shift-invariant;
// scores bounded) — no max tracking, no shuffles, no rescale. l via P@1 MFMA.
__global__ __launch_bounds__(256) void attn_kernel(
    const unsigned short* __restrict__ qb, const unsigned short* __restrict__ kb,
    const unsigned short* __restrict__ vt, unsigned short* __restrict__ ctx) {
    __shared__ __align__(16) unsigned short Ks[2][64 * 128];   // [key][dk]   2x16 KB
    __shared__ __align__(16) unsigned short Vs[2][128 * 64];   // [dk][key]   2x16 KB
    __shared__ __align__(16) unsigned short pbuf[4][16 * 68];  // stride 68: 2-way banks
    const int qt   = 31 - blockIdx.y;               // heavy tiles dispatched first
    const int u    = blockIdx.x;
    const int bh   = ((u & 7) << 2) | (u >> 3);     // same head -> same XCD (id%8)
    const int q0   = qt * 64;
    const int w    = threadIdx.x >> 6, lane = threadIdx.x & 63;
    const int lrow = lane & 15, quad = lane >> 4;
    const int qrow = q0 + w * 16;
    const float sc2 = 0.08838834764831845f * 1.4426950408889634f;  // DK^-.5 * log2e
    const short8 vone = {16256, 16256, 16256, 16256, 16256, 16256, 16256, 16256}; // bf16 1.0

    // Q A-frags (A[m=lane&15][k=quad*8+j], k-chunks of 32 over DK=128)
    short8 aq[4];
    const unsigned short* qbase = qb + ((size_t)bh * T_SEQ + qrow + lrow) * DK;
#pragma unroll
    for (int kk = 0; kk < 4; ++kk)
        aq[kk] = *(const short8*)(qbase + kk * 32 + quad * 8);

    f32x4 o[8];
#pragma unroll
    for (int d = 0; d < 8; ++d) o[d] = (f32x4){0.f, 0.f, 0.f, 0.f};
    f32x4 ol = (f32x4){0.f, 0.f, 0.f, 0.f};   // row sums of P (denominator)

    const unsigned short* kg0 = kb + (size_t)bh * T_SEQ * DK;
    const unsigned short* vg0 = vt + (size_t)bh * DK * T_SEQ;

    auto stage = [&](int kt, int sbuf) {
        const unsigned short* kg = kg0 + (size_t)kt * 64 * DK;
        const unsigned short* vg = vg0 + kt * 64;
        unsigned short* Kd = &Ks[sbuf][0];
        unsigned short* Vd = &Vs[sbuf][0];
#pragma unroll
        for (int j = 0; j < 4; ++j) {
            int c = (w * 4 + j) * 64 + lane;            // 0..1023
            int kr_ = c >> 4, kc = (c & 15) ^ (kr_ & 7);
            async_load16(kg + (size_t)kr_ * DK + kc * 8, Kd + c * 8);
            int vr = c >> 3, vc = (c & 7) ^ (vr & 7);
            async_load16(vg + (size_t)vr * T_SEQ + vc * 8, Vd + c * 8);
        }
    };

    stage(0, 0);
    for (int kt = 0; kt <= qt; ++kt) {
        __syncthreads();   // drains own vmcnt (incl. stage(kt)) then syncs waves
        if (kt < qt) stage(kt + 1, (kt + 1) & 1);
        const unsigned short* Kb = &Ks[kt & 1][0];
        const unsigned short* Vb = &Vs[kt & 1][0];

        // ---- S = Q K^T (16x64 per wave)
        f32x4 s[4];
#pragma unroll
        for (int nt = 0; nt < 4; ++nt) s[nt] = (f32x4){0.f, 0.f, 0.f, 0.f};
#pragma unroll
        for (int kk = 0; kk < 4; ++kk)
#pragma unroll
            for (int nt = 0; nt < 4; ++nt) {
                int row = nt * 16 + lrow;
                int kc = (kk * 4 + quad) ^ (row & 7);
                short8 bk = *(const short8*)(Kb + row * 128 + kc * 8);
                s[nt] = __builtin_amdgcn_mfma_f32_16x16x32_bf16(aq[kk], bk, s[nt], 0, 0, 0);
            }

        // ---- fixed-M softmax numerator: p = 2^(s*sc2 - 12); causal zero on diag
        const bool diag = (kt == qt);
        unsigned short* pb = &pbuf[w][0];
#pragma unroll
        for (int nt = 0; nt < 4; ++nt)
#pragma unroll
            for (int r = 0; r < 4; ++r) {
                float p = exp2f(fmaf(s[nt][r], sc2, -12.0f));
                if (diag && (nt * 16 + lrow > w * 16 + quad * 4 + r)) p = 0.f;
                pb[(quad * 4 + r) * 68 + nt * 16 + lrow] = f2bf(p);
            }
        __builtin_amdgcn_s_waitcnt(0xc07f);  // lgkmcnt(0): P writes visible
        short8 ap[2];
#pragma unroll
        for (int kk2 = 0; kk2 < 2; ++kk2)
            ap[kk2] = *(const short8*)(pb + lrow * 68 + kk2 * 32 + quad * 8);

        // ---- O += P V ; l += P @ ones
#pragma unroll
        for (int kk2 = 0; kk2 < 2; ++kk2)
            ol = __builtin_amdgcn_mfma_f32_16x16x32_bf16(ap[kk2], vone, ol, 0, 0, 0);
#pragma unroll
        for (int d = 0; d < 8; ++d)
#pragma unroll
            for (int kk2 = 0; kk2 < 2; ++kk2) {
                int row = d * 16 + lrow;
                int vc = (kk2 * 4 + quad) ^ (row & 7);
                short8 bv = *(const short8*)(Vb + row * 64 + vc * 8);
                o[d] = __builtin_amdgcn_mfma_f32_16x16x32_bf16(ap[kk2], bv, o[d], 0, 0, 0);
            }
    }

    // epilogue: ctx (b, t, h*DK+dk) bf16 ; divide by row sum (shift cancels)
    const int b = bh >> 4, h = bh & 15;
    float rl[4];
#pragma unroll
    for (int r = 0; r < 4; ++r) rl[r] = 1.0f / ol[r];
#pragma unroll
    for (int d = 0; d < 8; ++d)
#pragma unroll
        for (int r = 0; r < 4; ++r) {
            int row = qrow + quad * 4 + r;
            ctx[((size_t)(b * T_SEQ + row)) * DMODEL + h * DK + d * 16 + lrow] =
                f2bf(o[d][r] * rl[r]);
        }
}

// ---------------------------------------------------------------- launch
extern "C" void kernel_launch(void* const* d_in, const int* in_sizes, int n_in,
                              void* d_out, int out_size, void* d_ws, size_t ws_size,
                              hipStream_t stream) {
    const float* x     = (const float*)d_in[0];
    const float* freqs = (const float*)d_in[1];
    const float* Wqkv  = (const float*)d_in[2];
    const float* Wout  = (const float*)d_in[3];
    float* out = (float*)d_out;
    char* ws = (char*)d_ws;
    // workspace layout (96 MiB total); ctx aliases xb (dead after GEMM1)
    unsigned short* xb    = (unsigned short*)(ws);               // 16 MiB
    unsigned short* ctx   = (unsigned short*)(ws);               // 16 MiB (alias)
    unsigned short* wqkvT = (unsigned short*)(ws + 16777216);    // 24 MiB
    unsigned short* woutT = (unsigned short*)(ws + 41943040);    // 8 MiB
    unsigned short* qraw  = (unsigned short*)(ws + 50331648);    // 16 MiB
    unsigned short* kraw  = (unsigned short*)(ws + 67108864);    // 16 MiB
    unsigned short* vtb   = (unsigned short*)(ws + 83886080);    // 16 MiB

    cast_x_kernel<<<8192, 256, 0, stream>>>(x, xb, 2097152);
    wtrans_kernel<<<dim3(96, 32), 256, 0, stream>>>(Wqkv, wqkvT, DMODEL, NQKV);
    wtrans_kernel<<<dim3(32, 32), 256, 0, stream>>>(Wout, woutT, DMODEL, DMODEL);
    gemm_bt_kernel<1><<<dim3(48, 32), 256, 0, stream>>>(
        xb, wqkvT, nullptr, qraw, kraw, vtb, BATCH * T_SEQ, NQKV, DMODEL);
    rope_kernel<<<16384, 256, 0, stream>>>(qraw, kraw, freqs);
    attn_kernel<<<dim3(32, 32), 256, 0, stream>>>(qraw, kraw, vtb, ctx);
    gemm_bt_kernel<0><<<dim3(16, 32), 256, 0, stream>>>(
        ctx, woutT, out, nullptr, nullptr, nullptr, BATCH * T_SEQ, DMODEL, DMODEL);
}